// Round 3
// baseline (571.453 us; speedup 1.0000x reference)
//
#include <hip/hip_runtime.h>
#include <math.h>

#define N 4096
#define NB 256         // bands per column (16-row half-bands)
#define BANDSZ 16      // rows per band
#define KB 8           // slots per (band, col) cell
#define MAXDEG 128
#define NEG_SLOPE 0.2f
#define LN_EPS 1e-5f
#define GRID 1024

__device__ __forceinline__ float wave_reduce_sum(float v) {
    #pragma unroll
    for (int m = 32; m >= 1; m >>= 1) v += __shfl_xor(v, m, 64);
    return v;
}
__device__ __forceinline__ float wave_reduce_max(float v) {
    #pragma unroll
    for (int m = 32; m >= 1; m >>= 1) v = fmaxf(v, __shfl_xor(v, m, 64));
    return v;
}

// row-vector (lane=col) times 64x64 row-major W via shfl broadcast.
__device__ __forceinline__ float transform_row(float hv, const float* __restrict__ W,
                                               int lane) {
    float tr = 0.f;
    #pragma unroll
    for (int k = 0; k < 64; ++k)
        tr += __shfl(hv, k, 64) * W[k * 64 + lane];
    return tr;
}

// softmax over neighbors (j0: first 64, j1: next 64, deg total) + weighted
// aggregation of hwin rows + bias.
__device__ __forceinline__ float agg_core(int j0, int j1, int deg, float sd,
        const float* __restrict__ ssin, const float* __restrict__ hwin,
        const float* __restrict__ b, int lane) {
    float e0 = -1e30f, e1 = -1e30f;
    if (lane < deg)      { float v = ssin[j0] + sd; e0 = v > 0.f ? v : NEG_SLOPE * v; }
    if (lane + 64 < deg) { float v = ssin[j1] + sd; e1 = v > 0.f ? v : NEG_SLOPE * v; }
    float m = wave_reduce_max(fmaxf(e0, e1));
    float p0 = (lane < deg)      ? expf(e0 - m) : 0.f;
    float p1 = (lane + 64 < deg) ? expf(e1 - m) : 0.f;
    float Z = wave_reduce_sum(p0 + p1);
    float acc = 0.f;
    int d0 = min(deg, 64);
    #pragma unroll 8
    for (int n = 0; n < d0; ++n) {
        int   jj = __shfl(j0, n, 64);
        float p  = __shfl(p0, n, 64);
        acc += p * hwin[jj * 64 + lane];
    }
    #pragma unroll 4
    for (int n = 64; n < deg; ++n) {
        int   jj = __shfl(j1, n - 64, 64);
        float p  = __shfl(p1, n - 64, 64);
        acc += p * hwin[jj * 64 + lane];
    }
    return acc / Z + b[lane];
}

// One-shot grid barrier (counters pre-zeroed by hipMemsetAsync each launch).
// __threadfence() = device-scope fence: flushes/orders this XCD's writes
// before arrival; after the flag it prevents stale post-barrier reads.
__device__ __forceinline__ void grid_barrier(int* ctrl, int k) {
    __syncthreads();
    if (threadIdx.x == 0) {
        int* cnt  = ctrl + k * 32;        // 128 B apart
        int* flag = ctrl + k * 32 + 16;   // 64 B from its counter
        __threadfence();
        int prev = __hip_atomic_fetch_add(cnt, 1, __ATOMIC_RELAXED,
                                          __HIP_MEMORY_SCOPE_AGENT);
        if (prev == GRID - 1) {
            __hip_atomic_store(flag, 1, __ATOMIC_RELEASE, __HIP_MEMORY_SCOPE_AGENT);
        } else {
            while (__hip_atomic_load(flag, __ATOMIC_RELAXED,
                                     __HIP_MEMORY_SCOPE_AGENT) == 0)
                __builtin_amdgcn_s_sleep(4);
        }
        __threadfence();
    }
    __syncthreads();
}

// Fused: stage A (banded neighbor build over ALL 262144 threads, 16-row bands,
// + emb MLP + layer-0 transform) | bar | stage B (compact + agg0 + tr1) | bar |
// stage C (agg1 + tr2) | bar | stage D (agg2 + residual + LN + dot + finish).
__global__ void __launch_bounds__(256, 4) fused_gat(
        const float4* __restrict__ adj4, const int* __restrict__ timestep,
        const float* __restrict__ arr, const float* __restrict__ dep,
        const float* __restrict__ hard,
        const float* __restrict__ w1, const float* __restrict__ b1,
        const float* __restrict__ w2, const float* __restrict__ b2,
        const float* __restrict__ gat_w, const float* __restrict__ gat_asrc,
        const float* __restrict__ gat_adst, const float* __restrict__ gat_b,
        const float* __restrict__ vw, const float* __restrict__ vb,
        unsigned short* __restrict__ nbr2, unsigned char* __restrict__ cnt2,
        int* __restrict__ nbr_c, int* __restrict__ deg_arr,
        float* __restrict__ x, float* __restrict__ hwA, float* __restrict__ hwB,
        float* __restrict__ ssA, float* __restrict__ sdA,
        float* __restrict__ ssB, float* __restrict__ sdB,
        int* __restrict__ ctrl, float* __restrict__ out) {
    __shared__ int lds[4][MAXDEG];
    __shared__ float sp[4];
    int wave = threadIdx.x >> 6;
    int lane = threadIdx.x & 63;
    int i = blockIdx.x * 4 + wave;        // row owned by this wave in stages B-D

    // ---- stage A: build (this block's 256 threads scan 16 rows x 1024 cols)
    {
        int t    = blockIdx.x * 256 + threadIdx.x;   // 0..262143
        int cg   = t & 1023;                          // col group (4 cols)
        int hb   = t >> 10;                           // 0..255 (16-row band)
        int i0   = cg * 4;
        int jbase = hb * BANDSZ;
        int lc0 = 0, lc1 = 0, lc2 = 0, lc3 = 0;
        int b0  = (hb * N + i0) * KB;                 // 4 cells = one 64B line
        int b1_ = b0 + KB;
        int b2_ = b0 + 2 * KB;
        int b3_ = b0 + 3 * KB;
        #pragma unroll
        for (int batch = 0; batch < 2; ++batch) {
            float4 a[8];
            #pragma unroll
            for (int u = 0; u < 8; ++u)
                a[u] = adj4[(size_t)(jbase + batch * 8 + u) * 1024 + cg];
            #pragma unroll
            for (int u = 0; u < 8; ++u) {
                int j = jbase + batch * 8 + u;
                if (a[u].x != 0.f || j == i0)     { if (lc0 < KB) nbr2[b0  + lc0] = (unsigned short)j; ++lc0; }
                if (a[u].y != 0.f || j == i0 + 1) { if (lc1 < KB) nbr2[b1_ + lc1] = (unsigned short)j; ++lc1; }
                if (a[u].z != 0.f || j == i0 + 2) { if (lc2 < KB) nbr2[b2_ + lc2] = (unsigned short)j; ++lc2; }
                if (a[u].w != 0.f || j == i0 + 3) { if (lc3 < KB) nbr2[b3_ + lc3] = (unsigned short)j; ++lc3; }
            }
        }
        int cb = hb * N + i0;
        cnt2[cb]     = (unsigned char)(lc0 < KB ? lc0 : KB);
        cnt2[cb + 1] = (unsigned char)(lc1 < KB ? lc1 : KB);
        cnt2[cb + 2] = (unsigned char)(lc2 < KB ? lc2 : KB);
        cnt2[cb + 3] = (unsigned char)(lc3 < KB ? lc3 : KB);
    }
    // ---- stage A: emb MLP + layer-0 transform (one row per wave)
    {
        float ts = (float)(*timestep);
        float pr = (ts - arr[i]) / (dep[i] - arr[i]);
        float hd = hard[i];
        float t  = pr * w1[lane] + hd * w1[64 + lane] + b1[lane];
        float xv = b2[lane];
        #pragma unroll
        for (int k = 0; k < 64; ++k)
            xv += __shfl(t, k, 64) * w2[k * 64 + lane];
        x[i * 64 + lane] = xv;
        float tr = transform_row(xv, gat_w, lane);
        hwA[i * 64 + lane] = tr;
        float s1 = wave_reduce_sum(tr * gat_asrc[lane]);
        float s2 = wave_reduce_sum(tr * gat_adst[lane]);
        if (lane == 0) { ssA[i] = s1; sdA[i] = s2; }
    }
    grid_barrier(ctrl, 0);

    // ---- stage B: compact (lane owns 4 bands of row i) + agg0 + relu + tr1
    {
        int cell0 = (4 * lane)     * N + i;
        int cell1 = (4 * lane + 1) * N + i;
        int cell2 = (4 * lane + 2) * N + i;
        int cell3 = (4 * lane + 3) * N + i;
        int c0 = min((int)cnt2[cell0], KB);
        int c1 = min((int)cnt2[cell1], KB);
        int c2 = min((int)cnt2[cell2], KB);
        int c3 = min((int)cnt2[cell3], KB);
        int c  = c0 + c1 + c2 + c3;
        int inc = c;
        #pragma unroll
        for (int s = 1; s < 64; s <<= 1) {
            int t = __shfl_up(inc, s, 64);
            if (lane >= s) inc += t;
        }
        int off = inc - c;
        int deg = min(__shfl(inc, 63, 64), MAXDEG);
        {
            int o = off;
            int base0 = cell0 * KB;
            for (int k = 0; k < c0; ++k) { if (o < MAXDEG) lds[wave][o] = (int)nbr2[base0 + k]; ++o; }
            int base1 = cell1 * KB;
            for (int k = 0; k < c1; ++k) { if (o < MAXDEG) lds[wave][o] = (int)nbr2[base1 + k]; ++o; }
            int base2 = cell2 * KB;
            for (int k = 0; k < c2; ++k) { if (o < MAXDEG) lds[wave][o] = (int)nbr2[base2 + k]; ++o; }
            int base3 = cell3 * KB;
            for (int k = 0; k < c3; ++k) { if (o < MAXDEG) lds[wave][o] = (int)nbr2[base3 + k]; ++o; }
        }
        __syncthreads();
        int j0 = (lane < deg)      ? lds[wave][lane]      : 0;
        int j1 = (lane + 64 < deg) ? lds[wave][lane + 64] : 0;
        if (lane < deg)      nbr_c[i * MAXDEG + lane]      = j0;
        if (lane + 64 < deg) nbr_c[i * MAXDEG + lane + 64] = j1;
        if (lane == 0) deg_arr[i] = deg;
        float hv = fmaxf(agg_core(j0, j1, deg, sdA[i], ssA, hwA, gat_b, lane), 0.f);
        float tr = transform_row(hv, gat_w + 64 * 64, lane);
        hwB[i * 64 + lane] = tr;
        float s1 = wave_reduce_sum(tr * gat_asrc[64 + lane]);
        float s2 = wave_reduce_sum(tr * gat_adst[64 + lane]);
        if (lane == 0) { ssB[i] = s1; sdB[i] = s2; }
    }
    grid_barrier(ctrl, 1);

    // ---- stage C: agg1 + relu + tr2
    {
        int deg = deg_arr[i];
        int j0 = (lane < deg)      ? nbr_c[i * MAXDEG + lane]      : 0;
        int j1 = (lane + 64 < deg) ? nbr_c[i * MAXDEG + lane + 64] : 0;
        float hv = fmaxf(agg_core(j0, j1, deg, sdB[i], ssB, hwB, gat_b + 64, lane), 0.f);
        float tr = transform_row(hv, gat_w + 2 * 64 * 64, lane);
        hwA[i * 64 + lane] = tr;
        float s1 = wave_reduce_sum(tr * gat_asrc[128 + lane]);
        float s2 = wave_reduce_sum(tr * gat_adst[128 + lane]);
        if (lane == 0) { ssA[i] = s1; sdA[i] = s2; }
    }
    grid_barrier(ctrl, 2);

    // ---- stage D: agg2 + residual + layernorm + dot + atomic finish
    {
        int deg = deg_arr[i];
        int j0 = (lane < deg)      ? nbr_c[i * MAXDEG + lane]      : 0;
        int j1 = (lane + 64 < deg) ? nbr_c[i * MAXDEG + lane + 64] : 0;
        float hv = agg_core(j0, j1, deg, sdA[i], ssA, hwA, gat_b + 128, lane);
        float v  = x[i * 64 + lane] + hv;
        float mu = wave_reduce_sum(v) * (1.f / 64.f);
        float d  = v - mu;
        float var = wave_reduce_sum(d * d) * (1.f / 64.f);
        float ln  = d * rsqrtf(var + LN_EPS);
        float part = wave_reduce_sum(ln * vw[lane]);
        if (lane == 0) sp[wave] = part;
        __syncthreads();
        if (threadIdx.x == 0) {
            float bp = sp[0] + sp[1] + sp[2] + sp[3];
            float* accum = (float*)(ctrl + 96);
            int*   done  = ctrl + 112;
            atomicAdd(accum, bp);
            __threadfence();
            int old = atomicAdd(done, 1);
            if (old == GRID - 1) {
                float t = __hip_atomic_load(accum, __ATOMIC_RELAXED,
                                            __HIP_MEMORY_SCOPE_AGENT);
                out[0] = fmaxf(t * (1.f / (float)N) + vb[0], 0.f);
            }
        }
    }
}

extern "C" void kernel_launch(void* const* d_in, const int* in_sizes, int n_in,
                              void* d_out, int out_size, void* d_ws, size_t ws_size,
                              hipStream_t stream) {
    const float4* adj4      = (const float4*)d_in[0];
    const int*   timestep   = (const int*)  d_in[1];
    const float* arrivals   = (const float*)d_in[2];
    const float* departures = (const float*)d_in[3];
    const float* hard       = (const float*)d_in[4];
    // d_in[5] active_agents: unused by reference
    const float* emb_w1     = (const float*)d_in[6];
    const float* emb_b1     = (const float*)d_in[7];
    const float* emb_w2     = (const float*)d_in[8];
    const float* emb_b2     = (const float*)d_in[9];
    const float* gat_w      = (const float*)d_in[10];
    const float* gat_asrc   = (const float*)d_in[11];
    const float* gat_adst   = (const float*)d_in[12];
    const float* gat_b      = (const float*)d_in[13];
    const float* val_w      = (const float*)d_in[14];
    const float* val_b      = (const float*)d_in[15];

    const size_t MB = 1u << 20;
    char* ws = (char*)d_ws;
    unsigned short* nbr2 = (unsigned short*)(ws);            // 16 MB (256*4096*8 u16)
    unsigned char*  cnt2 = (unsigned char*) (ws + 16 * MB);  // 1 MB
    int*   nbr_c   = (int*)  (ws + 17 * MB);       // 2 MB
    int*   deg_arr = (int*)  (ws + 19 * MB);       // 16 KB
    float* x       = (float*)(ws + 20 * MB);       // 1 MB
    float* hwA     = (float*)(ws + 21 * MB);       // 1 MB
    float* hwB     = (float*)(ws + 22 * MB);       // 1 MB
    float* ssA     = (float*)(ws + 23 * MB);
    float* sdA     = (float*)(ws + 23 * MB + 65536);
    float* ssB     = (float*)(ws + 23 * MB + 131072);
    float* sdB     = (float*)(ws + 23 * MB + 196608);
    int*   ctrl    = (int*)  (ws + 24 * MB);       // barriers + accum + done

    (void)hipMemsetAsync(ctrl, 0, 512, stream);
    fused_gat<<<GRID, 256, 0, stream>>>(adj4, timestep, arrivals, departures, hard,
                                        emb_w1, emb_b1, emb_w2, emb_b2,
                                        gat_w, gat_asrc, gat_adst, gat_b,
                                        val_w, val_b,
                                        nbr2, cnt2, nbr_c, deg_arr,
                                        x, hwA, hwB, ssA, sdA, ssB, sdB,
                                        ctrl, (float*)d_out);
    (void)in_sizes; (void)n_in; (void)out_size; (void)ws_size;
}

// Round 4
// 188.648 us; speedup vs baseline: 3.0292x; 3.0292x over previous
//
#include <hip/hip_runtime.h>
#include <math.h>

#define N 4096
#define NB 128         // bands per column
#define BANDSZ 32      // rows per band
#define KB 8           // slots per (band, col) cell
#define MAXDEG 128
#define NEG_SLOPE 0.2f
#define LN_EPS 1e-5f

__device__ __forceinline__ float wave_reduce_sum(float v) {
    #pragma unroll
    for (int m = 32; m >= 1; m >>= 1) v += __shfl_xor(v, m, 64);
    return v;
}
__device__ __forceinline__ float wave_reduce_max(float v) {
    #pragma unroll
    for (int m = 32; m >= 1; m >>= 1) v = fmaxf(v, __shfl_xor(v, m, 64));
    return v;
}

// row-vector (lane=col) times 64x64 row-major W via shfl broadcast.
__device__ __forceinline__ float transform_row(float hv, const float* __restrict__ W,
                                               int lane) {
    float tr = 0.f;
    #pragma unroll
    for (int k = 0; k < 64; ++k)
        tr += __shfl(hv, k, 64) * W[k * 64 + lane];
    return tr;
}

// softmax over neighbors (j0: first 64, j1: next 64, deg total) + weighted
// aggregation of hwin rows + bias. Used by dispatch 2 (unchanged, verified).
__device__ __forceinline__ float agg_core(int j0, int j1, int deg, float sd,
        const float* __restrict__ ssin, const float* __restrict__ hwin,
        const float* __restrict__ b, int lane) {
    float e0 = -1e30f, e1 = -1e30f;
    if (lane < deg)      { float v = ssin[j0] + sd; e0 = v > 0.f ? v : NEG_SLOPE * v; }
    if (lane + 64 < deg) { float v = ssin[j1] + sd; e1 = v > 0.f ? v : NEG_SLOPE * v; }
    float m = wave_reduce_max(fmaxf(e0, e1));
    float p0 = (lane < deg)      ? expf(e0 - m) : 0.f;
    float p1 = (lane + 64 < deg) ? expf(e1 - m) : 0.f;
    float Z = wave_reduce_sum(p0 + p1);
    float acc = 0.f;
    int d0 = min(deg, 64);
    #pragma unroll 4
    for (int n = 0; n < d0; ++n) {
        int   jj = __shfl(j0, n, 64);
        float p  = __shfl(p0, n, 64);
        acc += p * hwin[jj * 64 + lane];
    }
    for (int n = 64; n < deg; ++n) {
        int   jj = __shfl(j1, n - 64, 64);
        float p  = __shfl(p1, n - 64, 64);
        acc += p * hwin[jj * 64 + lane];
    }
    return acc / Z + b[lane];
}

// Half-gather for the 2-wave-per-row split (dispatches 3/4): this wave sums
// neighbor slots [lo, hi). Softmax probs are computed redundantly+identically
// in both waves (same inputs, deterministic ops), so no cross-wave exchange
// is needed for m/Z — only the partial acc is combined via LDS.
__device__ __forceinline__ float agg_half(int j0, int j1, int deg, float sd,
        const float* __restrict__ ssin, const float* __restrict__ hwin,
        int lane, int lo, int hi, float* Zout) {
    float e0 = -1e30f, e1 = -1e30f;
    if (lane < deg)      { float v = ssin[j0] + sd; e0 = v > 0.f ? v : NEG_SLOPE * v; }
    if (lane + 64 < deg) { float v = ssin[j1] + sd; e1 = v > 0.f ? v : NEG_SLOPE * v; }
    float m = wave_reduce_max(fmaxf(e0, e1));
    float p0 = (lane < deg)      ? expf(e0 - m) : 0.f;
    float p1 = (lane + 64 < deg) ? expf(e1 - m) : 0.f;
    *Zout = wave_reduce_sum(p0 + p1);
    float acc = 0.f;
    int hi0 = min(hi, 64);
    #pragma unroll 4
    for (int n = lo; n < hi0; ++n) {          // slots below 64
        int   jj = __shfl(j0, n, 64);
        float p  = __shfl(p0, n, 64);
        acc += p * hwin[jj * 64 + lane];
    }
    #pragma unroll 2
    for (int n = (lo > 64 ? lo : 64); n < hi; ++n) {   // slots >= 64
        int   jj = __shfl(j1, n - 64, 64);
        float p  = __shfl(p1, n - 64, 64);
        acc += p * hwin[jj * 64 + lane];
    }
    return acc;
}

// ---- dispatch 1: banded neighbor build (atomic-free, batched float4 loads)
// + emb MLP + layer-0 transform.  Verified-optimal configuration (189-193 µs
// baseline) — byte-identical to the R12 version. NORMAL loads/stores
// (nontemporal regressed both ways).
__global__ void __launch_bounds__(256) prep_kernel(
        const float4* __restrict__ adj4, const int* __restrict__ timestep,
        const float* __restrict__ arr, const float* __restrict__ dep,
        const float* __restrict__ hard,
        const float* __restrict__ w1, const float* __restrict__ b1,
        const float* __restrict__ w2, const float* __restrict__ b2,
        const float* __restrict__ W0, const float* __restrict__ asrc,
        const float* __restrict__ adst,
        unsigned short* __restrict__ nbr2, unsigned char* __restrict__ cnt2,
        float* __restrict__ x, float* __restrict__ hwA,
        float* __restrict__ ssA, float* __restrict__ sdA,
        float* __restrict__ accum, int* __restrict__ done) {
    int wave = threadIdx.x >> 6;
    int lane = threadIdx.x & 63;
    if (blockIdx.x < 512) {
        int t    = blockIdx.x * 256 + threadIdx.x;   // 0..131071
        int cg   = t & 1023;                          // col group (4 cols)
        int band = t >> 10;                           // 0..127
        int i0   = cg * 4;
        int jbase = band * BANDSZ;
        int lc0 = 0, lc1 = 0, lc2 = 0, lc3 = 0;
        int b0  = (band * N + i0) * KB;               // 4 cells = one 64B line
        int b1  = b0 + KB;
        int b2_ = b0 + 2 * KB;
        int b3  = b0 + 3 * KB;
        #pragma unroll
        for (int batch = 0; batch < 4; ++batch) {
            float4 a[8];
            #pragma unroll
            for (int u = 0; u < 8; ++u)
                a[u] = adj4[(size_t)(jbase + batch * 8 + u) * 1024 + cg];
            #pragma unroll
            for (int u = 0; u < 8; ++u) {
                int j = jbase + batch * 8 + u;
                if (a[u].x != 0.f || j == i0)     { if (lc0 < KB) nbr2[b0  + lc0] = (unsigned short)j; ++lc0; }
                if (a[u].y != 0.f || j == i0 + 1) { if (lc1 < KB) nbr2[b1  + lc1] = (unsigned short)j; ++lc1; }
                if (a[u].z != 0.f || j == i0 + 2) { if (lc2 < KB) nbr2[b2_ + lc2] = (unsigned short)j; ++lc2; }
                if (a[u].w != 0.f || j == i0 + 3) { if (lc3 < KB) nbr2[b3  + lc3] = (unsigned short)j; ++lc3; }
            }
        }
        int cb = band * N + i0;                       // 4 consecutive u8
        cnt2[cb]     = (unsigned char)(lc0 < KB ? lc0 : KB);
        cnt2[cb + 1] = (unsigned char)(lc1 < KB ? lc1 : KB);
        cnt2[cb + 2] = (unsigned char)(lc2 < KB ? lc2 : KB);
        cnt2[cb + 3] = (unsigned char)(lc3 < KB ? lc3 : KB);
        if (blockIdx.x == 0 && threadIdx.x == 0) { *accum = 0.f; *done = 0; }
    } else {
        int row = (blockIdx.x - 512) * 4 + wave;      // one row per wave
        float ts = (float)(*timestep);
        float pr = (ts - arr[row]) / (dep[row] - arr[row]);
        float hd = hard[row];
        float t  = pr * w1[lane] + hd * w1[64 + lane] + b1[lane];
        float xv = b2[lane];
        #pragma unroll
        for (int k = 0; k < 64; ++k)
            xv += __shfl(t, k, 64) * w2[k * 64 + lane];
        x[row * 64 + lane] = xv;
        float tr = transform_row(xv, W0, lane);
        hwA[row * 64 + lane] = tr;
        float s1 = wave_reduce_sum(tr * asrc[lane]);
        float s2 = wave_reduce_sum(tr * adst[lane]);
        if (lane == 0) { ssA[row] = s1; sdA[row] = s2; }
    }
}

// ---- dispatch 2: compact banded lists (lane owns 2 bands of its row; wave
// prefix scan) + layer-0 aggregate + relu + layer-1 transform + scores.
// Unchanged from verified baseline.
__global__ void __launch_bounds__(256) compact_agg_tr(
        const unsigned short* __restrict__ nbr2, const unsigned char* __restrict__ cnt2,
        const float* __restrict__ hwin, const float* __restrict__ ssin,
        const float* __restrict__ sdin, const float* __restrict__ b,
        const float* __restrict__ W, const float* __restrict__ asrc,
        const float* __restrict__ adst,
        int* __restrict__ nbr_c, int* __restrict__ deg_arr,
        float* __restrict__ hwout, float* __restrict__ ssout,
        float* __restrict__ sdout) {
    __shared__ int lds[4][MAXDEG];
    int wave = threadIdx.x >> 6;
    int lane = threadIdx.x & 63;
    int i = blockIdx.x * 4 + wave;
    int cell0 = (2 * lane)     * N + i;   // transposed layout: band*N + col
    int cell1 = (2 * lane + 1) * N + i;
    int c0 = min((int)cnt2[cell0], KB);
    int c1 = min((int)cnt2[cell1], KB);
    int c  = c0 + c1;
    int inc = c;
    #pragma unroll
    for (int s = 1; s < 64; s <<= 1) {
        int t = __shfl_up(inc, s, 64);
        if (lane >= s) inc += t;
    }
    int off = inc - c;
    int deg = min(__shfl(inc, 63, 64), MAXDEG);
    {
        int base0 = cell0 * KB;
        int o = off;
        for (int k = 0; k < c0; ++k) { if (o < MAXDEG) lds[wave][o] = (int)nbr2[base0 + k]; ++o; }
        int base1 = cell1 * KB;
        for (int k = 0; k < c1; ++k) { if (o < MAXDEG) lds[wave][o] = (int)nbr2[base1 + k]; ++o; }
    }
    __syncthreads();
    int j0 = (lane < deg)      ? lds[wave][lane]      : 0;
    int j1 = (lane + 64 < deg) ? lds[wave][lane + 64] : 0;
    if (lane < deg)      nbr_c[i * MAXDEG + lane]      = j0;
    if (lane + 64 < deg) nbr_c[i * MAXDEG + lane + 64] = j1;
    if (lane == 0) deg_arr[i] = deg;
    float hv = fmaxf(agg_core(j0, j1, deg, sdin[i], ssin, hwin, b, lane), 0.f);
    float tr = transform_row(hv, W, lane);
    hwout[i * 64 + lane] = tr;
    float s1 = wave_reduce_sum(tr * asrc[lane]);
    float s2 = wave_reduce_sum(tr * adst[lane]);
    if (lane == 0) { ssout[i] = s1; sdout[i] = s2; }
}

// ---- dispatch 3: layer-1 aggregate + relu + layer-2 transform + scores.
// SPLIT version: 512-thr blocks, wave-pair per row (half=0 sums neighbor
// slots [0,h), half=1 sums [h,deg)); partial acc combined via LDS. Doubles
// occupancy (16 -> 32 waves/CU) and halves the serial gather chain.
__global__ void __launch_bounds__(512, 8) agg_tr(
        const float* __restrict__ hwin, const float* __restrict__ ssin,
        const float* __restrict__ sdin, const int* __restrict__ nbr_c,
        const int* __restrict__ deg_arr, const float* __restrict__ b,
        const float* __restrict__ W, const float* __restrict__ asrc,
        const float* __restrict__ adst,
        float* __restrict__ hwout, float* __restrict__ ssout,
        float* __restrict__ sdout) {
    __shared__ float accb[4][64];
    int w    = threadIdx.x >> 6;      // 0..7
    int lane = threadIdx.x & 63;
    int r    = w >> 1;                // row slot 0..3
    int half = w & 1;
    int i = blockIdx.x * 4 + r;
    int deg = deg_arr[i];
    int j0 = (lane < deg)      ? nbr_c[i * MAXDEG + lane]      : 0;
    int j1 = (lane + 64 < deg) ? nbr_c[i * MAXDEG + lane + 64] : 0;
    int h  = (deg + 1) >> 1;
    float Z;
    float acc = agg_half(j0, j1, deg, sdin[i], ssin, hwin, lane,
                         half ? h : 0, half ? deg : h, &Z);
    if (half) accb[r][lane] = acc;
    __syncthreads();
    if (!half) {
        acc += accb[r][lane];
        float hv = fmaxf(acc / Z + b[lane], 0.f);
        float tr = transform_row(hv, W, lane);
        hwout[i * 64 + lane] = tr;
        float s1 = wave_reduce_sum(tr * asrc[lane]);
        float s2 = wave_reduce_sum(tr * adst[lane]);
        if (lane == 0) { ssout[i] = s1; sdout[i] = s2; }
    }
}

// ---- dispatch 4: layer-2 aggregate + residual + layernorm + val_w dot +
// block atomicAdd + last-block finish. Same wave-pair split; still one
// atomicAdd per block (1024 total, as baseline).
__global__ void __launch_bounds__(512, 8) agg_final_finish(
        const float* __restrict__ hwin, const float* __restrict__ ssin,
        const float* __restrict__ sdin, const int* __restrict__ nbr_c,
        const int* __restrict__ deg_arr, const float* __restrict__ b,
        const float* __restrict__ x, const float* __restrict__ vw,
        const float* __restrict__ vb,
        float* __restrict__ accum, int* __restrict__ done,
        float* __restrict__ out) {
    __shared__ float accb[4][64];
    __shared__ float sp[4];
    int w    = threadIdx.x >> 6;
    int lane = threadIdx.x & 63;
    int r    = w >> 1;
    int half = w & 1;
    int i = blockIdx.x * 4 + r;
    int deg = deg_arr[i];
    int j0 = (lane < deg)      ? nbr_c[i * MAXDEG + lane]      : 0;
    int j1 = (lane + 64 < deg) ? nbr_c[i * MAXDEG + lane + 64] : 0;
    int h  = (deg + 1) >> 1;
    float Z;
    float acc = agg_half(j0, j1, deg, sdin[i], ssin, hwin, lane,
                         half ? h : 0, half ? deg : h, &Z);
    if (half) accb[r][lane] = acc;
    __syncthreads();
    if (!half) {
        acc += accb[r][lane];
        float hv = acc / Z + b[lane];
        float v  = x[i * 64 + lane] + hv;
        float mu = wave_reduce_sum(v) * (1.f / 64.f);
        float d  = v - mu;
        float var = wave_reduce_sum(d * d) * (1.f / 64.f);
        float ln  = d * rsqrtf(var + LN_EPS);
        float part = wave_reduce_sum(ln * vw[lane]);
        if (lane == 0) sp[r] = part;
    }
    __syncthreads();
    if (threadIdx.x == 0) {
        float bp = sp[0] + sp[1] + sp[2] + sp[3];
        atomicAdd(accum, bp);
        __threadfence();
        int old = atomicAdd(done, 1);
        if (old == (N / 4) - 1) {
            float t = __hip_atomic_load(accum, __ATOMIC_RELAXED,
                                        __HIP_MEMORY_SCOPE_AGENT);
            out[0] = fmaxf(t * (1.f / (float)N) + vb[0], 0.f);
        }
    }
}

extern "C" void kernel_launch(void* const* d_in, const int* in_sizes, int n_in,
                              void* d_out, int out_size, void* d_ws, size_t ws_size,
                              hipStream_t stream) {
    const float4* adj4      = (const float4*)d_in[0];
    const int*   timestep   = (const int*)  d_in[1];
    const float* arrivals   = (const float*)d_in[2];
    const float* departures = (const float*)d_in[3];
    const float* hard       = (const float*)d_in[4];
    // d_in[5] active_agents: unused by reference
    const float* emb_w1     = (const float*)d_in[6];
    const float* emb_b1     = (const float*)d_in[7];
    const float* emb_w2     = (const float*)d_in[8];
    const float* emb_b2     = (const float*)d_in[9];
    const float* gat_w      = (const float*)d_in[10];
    const float* gat_asrc   = (const float*)d_in[11];
    const float* gat_adst   = (const float*)d_in[12];
    const float* gat_b      = (const float*)d_in[13];
    const float* val_w      = (const float*)d_in[14];
    const float* val_b      = (const float*)d_in[15];

    const size_t MB = 1u << 20;
    char* ws = (char*)d_ws;
    unsigned short* nbr2 = (unsigned short*)(ws);           // 8 MB (128*4096*8 u16)
    unsigned char*  cnt2 = (unsigned char*) (ws + 8 * MB);  // 512 KB
    int*   nbr_c   = (int*)  (ws + 9 * MB);        // 2 MB
    int*   deg_arr = (int*)  (ws + 11 * MB);       // 16 KB
    float* x       = (float*)(ws + 12 * MB);       // 1 MB
    float* hwA     = (float*)(ws + 13 * MB);       // 1 MB
    float* hwB     = (float*)(ws + 14 * MB);       // 1 MB
    float* ssA     = (float*)(ws + 15 * MB);
    float* sdA     = (float*)(ws + 15 * MB + 65536);
    float* ssB     = (float*)(ws + 15 * MB + 131072);
    float* sdB     = (float*)(ws + 15 * MB + 196608);
    float* accum   = (float*)(ws + 16 * MB);
    int*   done    = (int*)  (ws + 16 * MB + 64);

    prep_kernel<<<1536, 256, 0, stream>>>(adj4, timestep, arrivals, departures, hard,
                                          emb_w1, emb_b1, emb_w2, emb_b2,
                                          gat_w, gat_asrc, gat_adst,
                                          nbr2, cnt2, x, hwA, ssA, sdA, accum, done);
    compact_agg_tr<<<N / 4, 256, 0, stream>>>(nbr2, cnt2, hwA, ssA, sdA, gat_b,
                                              gat_w + 64 * 64, gat_asrc + 64,
                                              gat_adst + 64,
                                              nbr_c, deg_arr, hwB, ssB, sdB);
    agg_tr<<<N / 4, 512, 0, stream>>>(hwB, ssB, sdB, nbr_c, deg_arr, gat_b + 64,
                                      gat_w + 2 * 64 * 64, gat_asrc + 128,
                                      gat_adst + 128, hwA, ssA, sdA);
    agg_final_finish<<<N / 4, 512, 0, stream>>>(hwA, ssA, sdA, nbr_c, deg_arr,
                                                gat_b + 128, x, val_w, val_b,
                                                accum, done, (float*)d_out);
    (void)in_sizes; (void)n_in; (void)out_size; (void)ws_size;
}

// Round 5
// 186.138 us; speedup vs baseline: 3.0701x; 1.0135x over previous
//
#include <hip/hip_runtime.h>
#include <math.h>

#define N 4096
#define NB 128         // bands per column
#define BANDSZ 32      // rows per band
#define MAXDEG 128
#define NEG_SLOPE 0.2f
#define LN_EPS 1e-5f

__device__ __forceinline__ float wave_reduce_sum(float v) {
    #pragma unroll
    for (int m = 32; m >= 1; m >>= 1) v += __shfl_xor(v, m, 64);
    return v;
}
__device__ __forceinline__ float wave_reduce_max(float v) {
    #pragma unroll
    for (int m = 32; m >= 1; m >>= 1) v = fmaxf(v, __shfl_xor(v, m, 64));
    return v;
}

// row-vector (lane=col) times 64x64 row-major W via shfl broadcast.
__device__ __forceinline__ float transform_row(float hv, const float* __restrict__ W,
                                               int lane) {
    float tr = 0.f;
    #pragma unroll
    for (int k = 0; k < 64; ++k)
        tr += __shfl(hv, k, 64) * W[k * 64 + lane];
    return tr;
}

// softmax over neighbors (j0: first 64, j1: next 64, deg total) + weighted
// aggregation of hwin rows + bias. Used by dispatch 2 (verified).
__device__ __forceinline__ float agg_core(int j0, int j1, int deg, float sd,
        const float* __restrict__ ssin, const float* __restrict__ hwin,
        const float* __restrict__ b, int lane) {
    float e0 = -1e30f, e1 = -1e30f;
    if (lane < deg)      { float v = ssin[j0] + sd; e0 = v > 0.f ? v : NEG_SLOPE * v; }
    if (lane + 64 < deg) { float v = ssin[j1] + sd; e1 = v > 0.f ? v : NEG_SLOPE * v; }
    float m = wave_reduce_max(fmaxf(e0, e1));
    float p0 = (lane < deg)      ? expf(e0 - m) : 0.f;
    float p1 = (lane + 64 < deg) ? expf(e1 - m) : 0.f;
    float Z = wave_reduce_sum(p0 + p1);
    float acc = 0.f;
    int d0 = min(deg, 64);
    #pragma unroll 4
    for (int n = 0; n < d0; ++n) {
        int   jj = __shfl(j0, n, 64);
        float p  = __shfl(p0, n, 64);
        acc += p * hwin[jj * 64 + lane];
    }
    for (int n = 64; n < deg; ++n) {
        int   jj = __shfl(j1, n - 64, 64);
        float p  = __shfl(p1, n - 64, 64);
        acc += p * hwin[jj * 64 + lane];
    }
    return acc / Z + b[lane];
}

// Half-gather for the 2-wave-per-row split (dispatches 3/4). Softmax probs
// computed redundantly+identically in both waves; partial acc via LDS.
__device__ __forceinline__ float agg_half(int j0, int j1, int deg, float sd,
        const float* __restrict__ ssin, const float* __restrict__ hwin,
        int lane, int lo, int hi, float* Zout) {
    float e0 = -1e30f, e1 = -1e30f;
    if (lane < deg)      { float v = ssin[j0] + sd; e0 = v > 0.f ? v : NEG_SLOPE * v; }
    if (lane + 64 < deg) { float v = ssin[j1] + sd; e1 = v > 0.f ? v : NEG_SLOPE * v; }
    float m = wave_reduce_max(fmaxf(e0, e1));
    float p0 = (lane < deg)      ? expf(e0 - m) : 0.f;
    float p1 = (lane + 64 < deg) ? expf(e1 - m) : 0.f;
    *Zout = wave_reduce_sum(p0 + p1);
    float acc = 0.f;
    int hi0 = min(hi, 64);
    #pragma unroll 4
    for (int n = lo; n < hi0; ++n) {          // slots below 64
        int   jj = __shfl(j0, n, 64);
        float p  = __shfl(p0, n, 64);
        acc += p * hwin[jj * 64 + lane];
    }
    #pragma unroll 2
    for (int n = (lo > 64 ? lo : 64); n < hi; ++n) {   // slots >= 64
        int   jj = __shfl(j1, n - 64, 64);
        float p  = __shfl(p1, n - 64, 64);
        acc += p * hwin[jj * 64 + lane];
    }
    return acc;
}

// ---- dispatch 1: BITMASK neighbor build + emb MLP + layer-0 transform.
// Build: thread owns 4 consecutive cols x one 32-row band; emits 4 x u32
// bitmasks (bit u = adj[jbase+u][col] != 0) as ONE coalesced uint4 store
// into bm[band][col] (2 MB total). Replaces the 8.5 MB slot-list append
// (serial lc chains, scattered u16 stores) of the prior version. Neighbor
// ORDER is preserved: bits LSB-first = j ascending, bands ascending.
// Blocks [512,1536): emb+tr0, one row per wave (verified structure).
__global__ void __launch_bounds__(256) prep_kernel(
        const float4* __restrict__ adj4, const int* __restrict__ timestep,
        const float* __restrict__ arr, const float* __restrict__ dep,
        const float* __restrict__ hard,
        const float* __restrict__ w1, const float* __restrict__ b1,
        const float* __restrict__ w2, const float* __restrict__ b2,
        const float* __restrict__ W0, const float* __restrict__ asrc,
        const float* __restrict__ adst,
        uint4* __restrict__ bm4,
        float* __restrict__ x, float* __restrict__ hwA,
        float* __restrict__ ssA, float* __restrict__ sdA,
        float* __restrict__ accum, int* __restrict__ done) {
    int wave = threadIdx.x >> 6;
    int lane = threadIdx.x & 63;
    if (blockIdx.x < 512) {
        int t    = blockIdx.x * 256 + threadIdx.x;   // 0..131071
        int cg   = t & 1023;                          // col group (4 cols)
        int band = t >> 10;                           // 0..127
        int jbase = band * BANDSZ;
        unsigned m0 = 0u, m1 = 0u, m2 = 0u, m3 = 0u;
        #pragma unroll
        for (int batch = 0; batch < 4; ++batch) {
            float4 a[8];
            #pragma unroll
            for (int u = 0; u < 8; ++u)
                a[u] = adj4[(size_t)(jbase + batch * 8 + u) * 1024 + cg];
            #pragma unroll
            for (int u = 0; u < 8; ++u) {
                unsigned bit = batch * 8 + u;
                m0 |= (unsigned)(a[u].x != 0.f) << bit;
                m1 |= (unsigned)(a[u].y != 0.f) << bit;
                m2 |= (unsigned)(a[u].z != 0.f) << bit;
                m3 |= (unsigned)(a[u].w != 0.f) << bit;
            }
        }
        uint4 m; m.x = m0; m.y = m1; m.z = m2; m.w = m3;
        bm4[band * 1024 + cg] = m;                    // bm[band][i0..i0+3]
        if (blockIdx.x == 0 && threadIdx.x == 0) { *accum = 0.f; *done = 0; }
    } else {
        int row = (blockIdx.x - 512) * 4 + wave;      // one row per wave
        float ts = (float)(*timestep);
        float pr = (ts - arr[row]) / (dep[row] - arr[row]);
        float hd = hard[row];
        float t  = pr * w1[lane] + hd * w1[64 + lane] + b1[lane];
        float xv = b2[lane];
        #pragma unroll
        for (int k = 0; k < 64; ++k)
            xv += __shfl(t, k, 64) * w2[k * 64 + lane];
        x[row * 64 + lane] = xv;
        float tr = transform_row(xv, W0, lane);
        hwA[row * 64 + lane] = tr;
        float s1 = wave_reduce_sum(tr * asrc[lane]);
        float s2 = wave_reduce_sum(tr * adst[lane]);
        if (lane == 0) { ssA[row] = s1; sdA[row] = s2; }
    }
}

// ---- dispatch 2: mask->index compaction (lane owns 2 bands of its row;
// popc + wave prefix scan + LSB-first bit extract) + layer-0 aggregate +
// relu + layer-1 transform + scores. Self-loop OR'd into the owning band's
// mask (preserves j-sorted insertion position).
__global__ void __launch_bounds__(256) compact_agg_tr(
        const unsigned* __restrict__ bm,
        const float* __restrict__ hwin, const float* __restrict__ ssin,
        const float* __restrict__ sdin, const float* __restrict__ b,
        const float* __restrict__ W, const float* __restrict__ asrc,
        const float* __restrict__ adst,
        int* __restrict__ nbr_c, int* __restrict__ deg_arr,
        float* __restrict__ hwout, float* __restrict__ ssout,
        float* __restrict__ sdout) {
    __shared__ int lds[4][MAXDEG];
    int wave = threadIdx.x >> 6;
    int lane = threadIdx.x & 63;
    int i = blockIdx.x * 4 + wave;
    unsigned m0 = bm[(2 * lane)     * N + i];
    unsigned m1 = bm[(2 * lane + 1) * N + i];
    int selfband = i >> 5;                    // self-loop: bit i&31 of band i>>5
    if (2 * lane     == selfband) m0 |= 1u << (i & 31);
    if (2 * lane + 1 == selfband) m1 |= 1u << (i & 31);
    int c0 = __popc(m0);
    int c1 = __popc(m1);
    int c  = c0 + c1;
    int inc = c;
    #pragma unroll
    for (int s = 1; s < 64; s <<= 1) {
        int t = __shfl_up(inc, s, 64);
        if (lane >= s) inc += t;
    }
    int off = inc - c;
    int deg = min(__shfl(inc, 63, 64), MAXDEG);
    {
        int o = off;
        unsigned mm = m0; int base = (2 * lane) * 32;
        while (mm) { int bit = __ffs(mm) - 1; mm &= mm - 1;
                     if (o < MAXDEG) lds[wave][o] = base + bit; ++o; }
        mm = m1; base = (2 * lane + 1) * 32;
        while (mm) { int bit = __ffs(mm) - 1; mm &= mm - 1;
                     if (o < MAXDEG) lds[wave][o] = base + bit; ++o; }
    }
    __syncthreads();
    int j0 = (lane < deg)      ? lds[wave][lane]      : 0;
    int j1 = (lane + 64 < deg) ? lds[wave][lane + 64] : 0;
    if (lane < deg)      nbr_c[i * MAXDEG + lane]      = j0;
    if (lane + 64 < deg) nbr_c[i * MAXDEG + lane + 64] = j1;
    if (lane == 0) deg_arr[i] = deg;
    float hv = fmaxf(agg_core(j0, j1, deg, sdin[i], ssin, hwin, b, lane), 0.f);
    float tr = transform_row(hv, W, lane);
    hwout[i * 64 + lane] = tr;
    float s1 = wave_reduce_sum(tr * asrc[lane]);
    float s2 = wave_reduce_sum(tr * adst[lane]);
    if (lane == 0) { ssout[i] = s1; sdout[i] = s2; }
}

// ---- dispatch 3: layer-1 aggregate + relu + layer-2 transform + scores.
// 512-thr blocks, wave-pair per row (verified R4: 188.6 µs, absmax 0.0).
__global__ void __launch_bounds__(512, 8) agg_tr(
        const float* __restrict__ hwin, const float* __restrict__ ssin,
        const float* __restrict__ sdin, const int* __restrict__ nbr_c,
        const int* __restrict__ deg_arr, const float* __restrict__ b,
        const float* __restrict__ W, const float* __restrict__ asrc,
        const float* __restrict__ adst,
        float* __restrict__ hwout, float* __restrict__ ssout,
        float* __restrict__ sdout) {
    __shared__ float accb[4][64];
    int w    = threadIdx.x >> 6;      // 0..7
    int lane = threadIdx.x & 63;
    int r    = w >> 1;                // row slot 0..3
    int half = w & 1;
    int i = blockIdx.x * 4 + r;
    int deg = deg_arr[i];
    int j0 = (lane < deg)      ? nbr_c[i * MAXDEG + lane]      : 0;
    int j1 = (lane + 64 < deg) ? nbr_c[i * MAXDEG + lane + 64] : 0;
    int h  = (deg + 1) >> 1;
    float Z;
    float acc = agg_half(j0, j1, deg, sdin[i], ssin, hwin, lane,
                         half ? h : 0, half ? deg : h, &Z);
    if (half) accb[r][lane] = acc;
    __syncthreads();
    if (!half) {
        acc += accb[r][lane];
        float hv = fmaxf(acc / Z + b[lane], 0.f);
        float tr = transform_row(hv, W, lane);
        hwout[i * 64 + lane] = tr;
        float s1 = wave_reduce_sum(tr * asrc[lane]);
        float s2 = wave_reduce_sum(tr * adst[lane]);
        if (lane == 0) { ssout[i] = s1; sdout[i] = s2; }
    }
}

// ---- dispatch 4: layer-2 aggregate + residual + layernorm + val_w dot +
// block atomicAdd + last-block finish (wave-pair split, verified R4).
__global__ void __launch_bounds__(512, 8) agg_final_finish(
        const float* __restrict__ hwin, const float* __restrict__ ssin,
        const float* __restrict__ sdin, const int* __restrict__ nbr_c,
        const int* __restrict__ deg_arr, const float* __restrict__ b,
        const float* __restrict__ x, const float* __restrict__ vw,
        const float* __restrict__ vb,
        float* __restrict__ accum, int* __restrict__ done,
        float* __restrict__ out) {
    __shared__ float accb[4][64];
    __shared__ float sp[4];
    int w    = threadIdx.x >> 6;
    int lane = threadIdx.x & 63;
    int r    = w >> 1;
    int half = w & 1;
    int i = blockIdx.x * 4 + r;
    int deg = deg_arr[i];
    int j0 = (lane < deg)      ? nbr_c[i * MAXDEG + lane]      : 0;
    int j1 = (lane + 64 < deg) ? nbr_c[i * MAXDEG + lane + 64] : 0;
    int h  = (deg + 1) >> 1;
    float Z;
    float acc = agg_half(j0, j1, deg, sdin[i], ssin, hwin, lane,
                         half ? h : 0, half ? deg : h, &Z);
    if (half) accb[r][lane] = acc;
    __syncthreads();
    if (!half) {
        acc += accb[r][lane];
        float hv = acc / Z + b[lane];
        float v  = x[i * 64 + lane] + hv;
        float mu = wave_reduce_sum(v) * (1.f / 64.f);
        float d  = v - mu;
        float var = wave_reduce_sum(d * d) * (1.f / 64.f);
        float ln  = d * rsqrtf(var + LN_EPS);
        float part = wave_reduce_sum(ln * vw[lane]);
        if (lane == 0) sp[r] = part;
    }
    __syncthreads();
    if (threadIdx.x == 0) {
        float bp = sp[0] + sp[1] + sp[2] + sp[3];
        atomicAdd(accum, bp);
        __threadfence();
        int old = atomicAdd(done, 1);
        if (old == (N / 4) - 1) {
            float t = __hip_atomic_load(accum, __ATOMIC_RELAXED,
                                        __HIP_MEMORY_SCOPE_AGENT);
            out[0] = fmaxf(t * (1.f / (float)N) + vb[0], 0.f);
        }
    }
}

extern "C" void kernel_launch(void* const* d_in, const int* in_sizes, int n_in,
                              void* d_out, int out_size, void* d_ws, size_t ws_size,
                              hipStream_t stream) {
    const float4* adj4      = (const float4*)d_in[0];
    const int*   timestep   = (const int*)  d_in[1];
    const float* arrivals   = (const float*)d_in[2];
    const float* departures = (const float*)d_in[3];
    const float* hard       = (const float*)d_in[4];
    // d_in[5] active_agents: unused by reference
    const float* emb_w1     = (const float*)d_in[6];
    const float* emb_b1     = (const float*)d_in[7];
    const float* emb_w2     = (const float*)d_in[8];
    const float* emb_b2     = (const float*)d_in[9];
    const float* gat_w      = (const float*)d_in[10];
    const float* gat_asrc   = (const float*)d_in[11];
    const float* gat_adst   = (const float*)d_in[12];
    const float* gat_b      = (const float*)d_in[13];
    const float* val_w      = (const float*)d_in[14];
    const float* val_b      = (const float*)d_in[15];

    const size_t MB = 1u << 20;
    char* ws = (char*)d_ws;
    unsigned* bm   = (unsigned*)(ws);              // 2 MB (128*4096 u32 masks)
    int*   nbr_c   = (int*)  (ws + 4 * MB);        // 2 MB
    int*   deg_arr = (int*)  (ws + 6 * MB);        // 16 KB
    float* x       = (float*)(ws + 7 * MB);        // 1 MB
    float* hwA     = (float*)(ws + 8 * MB);        // 1 MB
    float* hwB     = (float*)(ws + 9 * MB);        // 1 MB
    float* ssA     = (float*)(ws + 10 * MB);
    float* sdA     = (float*)(ws + 10 * MB + 65536);
    float* ssB     = (float*)(ws + 10 * MB + 131072);
    float* sdB     = (float*)(ws + 10 * MB + 196608);
    float* accum   = (float*)(ws + 11 * MB);
    int*   done    = (int*)  (ws + 11 * MB + 64);

    prep_kernel<<<1536, 256, 0, stream>>>(adj4, timestep, arrivals, departures, hard,
                                          emb_w1, emb_b1, emb_w2, emb_b2,
                                          gat_w, gat_asrc, gat_adst,
                                          (uint4*)bm, x, hwA, ssA, sdA, accum, done);
    compact_agg_tr<<<N / 4, 256, 0, stream>>>(bm, hwA, ssA, sdA, gat_b,
                                              gat_w + 64 * 64, gat_asrc + 64,
                                              gat_adst + 64,
                                              nbr_c, deg_arr, hwB, ssB, sdB);
    agg_tr<<<N / 4, 512, 0, stream>>>(hwB, ssB, sdB, nbr_c, deg_arr, gat_b + 64,
                                      gat_w + 2 * 64 * 64, gat_asrc + 128,
                                      gat_adst + 128, hwA, ssA, sdA);
    agg_final_finish<<<N / 4, 512, 0, stream>>>(hwA, ssA, sdA, nbr_c, deg_arr,
                                                gat_b + 128, x, val_w, val_b,
                                                accum, done, (float*)d_out);
    (void)in_sizes; (void)n_in; (void)out_size; (void)ws_size;
}